// Round 9
// baseline (2688.258 us; speedup 1.0000x reference)
//
#include <hip/hip_runtime.h>
#include <hip/hip_bf16.h>

#define D_IN 256
#define D_OUT 128
#define LN_EPS 1e-5f
#define NSUB 2048          // sub-buckets of 64 nodes: sub = dst >> 6
#define NCHUNK 256         // edge chunks (one block each) in count/part

typedef short bf16x8 __attribute__((ext_vector_type(8)));
typedef float f32x4 __attribute__((ext_vector_type(4)));
typedef unsigned short ushort_t;

__device__ __forceinline__ float b2f(ushort_t u) {
    union { unsigned int i; float f; } v; v.i = (unsigned int)u << 16; return v.f;
}
__device__ __forceinline__ ushort_t f2b(float f) {
    __hip_bfloat16 h = __float2bfloat16(f);
    return *reinterpret_cast<ushort_t*>(&h);
}

// ---------------- Kernel 0: pack+transpose f32 weights into bf16 Wt[n][k], n = [W | res_w] cols
__global__ void k_transpose(const float* __restrict__ w, const float* __restrict__ rw,
                            ushort_t* __restrict__ wt) {
    int idx = blockIdx.x * 256 + threadIdx.x;   // 65536 total
    int n = idx >> 8, k = idx & 255;
    float v = (n < 128) ? w[k * 128 + n] : rw[k * 128 + (n - 128)];
    wt[idx] = f2b(v);
}

// ---------------- Kernel 1: FUSED dual-GEMM + edge sub-bucket histogram (independent roles)
// blocks [0, gb)        : 64-row MFMA gemm tile (software-pipelined K-loop)
// blocks [gb, gb+NCHUNK): per-chunk histogram over 2048 sub-buckets -> cntmat[chunk][sub]
__launch_bounds__(256)
__global__ void k_gemm_count(const float* __restrict__ x, const ushort_t* __restrict__ wt,
                             const float* __restrict__ bias, const float* __restrict__ res_b,
                             ushort_t* __restrict__ support, float* __restrict__ out,
                             const int* __restrict__ ei, int* __restrict__ cntmat,
                             int n_nodes, int E, int chunk, int gb) {
    __shared__ ushort_t As[64 * 40];
    __shared__ ushort_t Bs[256 * 40];
    __shared__ int h[NSUB];

    const int tid = threadIdx.x;

    if (blockIdx.x >= gb) {
        // ---- count role ----
        int c = blockIdx.x - gb;
#pragma unroll
        for (int i = 0; i < 8; i++) h[i * 256 + tid] = 0;
        __syncthreads();
        int lo = c * chunk, hi = min(lo + chunk, E);
        for (int e = lo + tid; e < hi; e += 256)
            atomicAdd(&h[(unsigned)ei[E + e] >> 6], 1);
        __syncthreads();
#pragma unroll
        for (int i = 0; i < 8; i++)
            cntmat[c * NSUB + i * 256 + tid] = h[i * 256 + tid];   // coalesced row write
        return;
    }

    // ---- gemm role ----
    const int m0 = blockIdx.x * 64;
    const int wv = tid >> 6, lane = tid & 63;
    const int lm = lane & 15, quad = lane >> 4;
    const int mh = wv >> 1;
    const int nh = wv & 1;

    f32x4 acc[2][8];
#pragma unroll
    for (int i = 0; i < 2; i++)
#pragma unroll
        for (int j = 0; j < 8; j++) acc[i][j] = 0.0f;

    const int arow = tid >> 2, aseg = tid & 3;
    const bool arow_ok = (m0 + arow) < n_nodes;
    const float* xrow = x + (long)(m0 + arow) * D_IN + aseg * 8;
    const ushort_t* wrow = wt + (long)arow * 256 + aseg * 8;   // brow == arow

    f32x4 p0 = {0.f, 0.f, 0.f, 0.f}, p1 = {0.f, 0.f, 0.f, 0.f};
    if (arow_ok) { p0 = *(const f32x4*)(xrow); p1 = *(const f32x4*)(xrow + 4); }
    bf16x8 bv[4];
#pragma unroll
    for (int i = 0; i < 4; i++)
        bv[i] = *(const bf16x8*)(wrow + (long)i * 64 * 256);

    for (int kc = 0; kc < 8; kc++) {
        __syncthreads();
        {
            bf16x8 av;
#pragma unroll
            for (int j = 0; j < 4; j++) { av[j] = (short)f2b(p0[j]); av[4 + j] = (short)f2b(p1[j]); }
            *(bf16x8*)(&As[arow * 40 + aseg * 8]) = av;
#pragma unroll
            for (int i = 0; i < 4; i++)
                *(bf16x8*)(&Bs[(arow + i * 64) * 40 + aseg * 8]) = bv[i];
        }
        if (kc < 7) {
            if (arow_ok) {
                p0 = *(const f32x4*)(xrow + (kc + 1) * 32);
                p1 = *(const f32x4*)(xrow + (kc + 1) * 32 + 4);
            }
#pragma unroll
            for (int i = 0; i < 4; i++)
                bv[i] = *(const bf16x8*)(wrow + (long)i * 64 * 256 + (kc + 1) * 32);
        }
        __syncthreads();

        bf16x8 afr0 = *(const bf16x8*)(&As[(mh * 32 + lm) * 40 + quad * 8]);
        bf16x8 afr1 = *(const bf16x8*)(&As[(mh * 32 + 16 + lm) * 40 + quad * 8]);
#pragma unroll
        for (int nt = 0; nt < 8; nt++) {
            bf16x8 bfr = *(const bf16x8*)(&Bs[(nh * 128 + nt * 16 + lm) * 40 + quad * 8]);
            acc[0][nt] = __builtin_amdgcn_mfma_f32_16x16x32_bf16(afr0, bfr, acc[0][nt], 0, 0, 0);
            acc[1][nt] = __builtin_amdgcn_mfma_f32_16x16x32_bf16(afr1, bfr, acc[1][nt], 0, 0, 0);
        }
    }

#pragma unroll
    for (int i = 0; i < 2; i++) {
#pragma unroll
        for (int nt = 0; nt < 8; nt++) {
            int col = nh * 128 + nt * 16 + lm;
#pragma unroll
            for (int r = 0; r < 4; r++) {
                int node = m0 + mh * 32 + i * 16 + quad * 4 + r;
                if (node >= n_nodes) continue;
                float v = acc[i][nt][r];
                if (col < 128) {
                    support[(long)node * 128 + col] = f2b(v);
                } else {
                    int c2 = col - 128;
                    float t = v + res_b[c2];
                    t = t > 0.0f ? t : 0.0f;
                    out[(long)node * 128 + c2] = t + bias[c2];
                }
            }
        }
    }
}

// ---------------- Kernel 2a: scan each sub-bucket across chunks (exclusive), rowsum out
// one block per sub-bucket; reads cntmat[c][b] column-strided (cold pass, tiny)
__launch_bounds__(256)
__global__ void k_scan1(int* __restrict__ cntmat, int* __restrict__ rowsum) {
    __shared__ int sh[256];
    int b = blockIdx.x, t = threadIdx.x;
    int v = cntmat[t * NSUB + b];
    sh[t] = v;
    __syncthreads();
    for (int off = 1; off < 256; off <<= 1) {
        int x = sh[t]; int add = (t >= off) ? sh[t - off] : 0;
        __syncthreads(); sh[t] = x + add; __syncthreads();
    }
    cntmat[t * NSUB + b] = sh[t] - v;
    if (t == 255) rowsum[b] = sh[255];
}

// ---------------- Kernel 2b: scan 2048 sub-bucket sums -> sub_base
__launch_bounds__(256)
__global__ void k_scan2(const int* __restrict__ rowsum, int* __restrict__ sub_base, int E) {
    __shared__ int sh[256];
    int t = threadIdx.x;
    int v[8]; int s = 0;
#pragma unroll
    for (int i = 0; i < 8; i++) { v[i] = rowsum[t * 8 + i]; s += v[i]; }
    sh[t] = s;
    __syncthreads();
    for (int off = 1; off < 256; off <<= 1) {
        int x = sh[t]; int add = (t >= off) ? sh[t - off] : 0;
        __syncthreads(); sh[t] = x + add; __syncthreads();
    }
    int excl = sh[t] - s;
#pragma unroll
    for (int i = 0; i < 8; i++) { sub_base[t * 8 + i] = excl; excl += v[i]; }
    if (t == 255) sub_base[NSUB] = excl;   // == E
}

// ---------------- Kernel 3: partition edges into sub-buckets (block-private sub-regions)
// rec = { src | dl<<17 , w_f32 }  (8B fused record, single scattered stream)
__launch_bounds__(256)
__global__ void k_part(const int* __restrict__ ei, const float* __restrict__ ew,
                       const int* __restrict__ cntmat, const int* __restrict__ sub_base,
                       int2* __restrict__ rec, int E, int chunk) {
    __shared__ int cur[NSUB];
    int c = blockIdx.x, t = threadIdx.x;
#pragma unroll
    for (int i = 0; i < 8; i++) {
        int b = i * 256 + t;
        cur[b] = sub_base[b] + cntmat[c * NSUB + b];   // coalesced row read
    }
    __syncthreads();
    int lo = c * chunk, hi = min(lo + chunk, E);
    for (int e = lo + t; e < hi; e += 256) {
        int src = ei[e];
        int dst = ei[E + e];
        float w = ew[e];
        int b = (unsigned)dst >> 6;
        int pos = atomicAdd(&cur[b], 1);
        int2 r; r.x = src | ((dst & 63) << 17); r.y = __float_as_int(w);
        rec[pos] = r;
    }
}

// ---------------- Kernel 4: sub-bucket aggregate (LDS f32 accum) + residual + LayerNorm
// one block per 64-node sub-bucket; no node-sort needed.
__launch_bounds__(256)
__global__ void k_agg_ln(const ushort_t* __restrict__ support, const int* __restrict__ sub_base,
                         const int2* __restrict__ rec,
                         const float* __restrict__ gamma, const float* __restrict__ beta,
                         float* __restrict__ out, int n_nodes) {
    __shared__ float acc[64 * 128];    // 32 KB
    int sb = blockIdx.x, tid = threadIdx.x;
    int wv = tid >> 6, lane = tid & 63;

    {
        f32x4 z = {0.f, 0.f, 0.f, 0.f};
        f32x4* av = (f32x4*)acc;
        for (int i = tid; i < 64 * 128 / 4; i += 256) av[i] = z;
    }
    __syncthreads();

    int start = sub_base[sb], end = sub_base[sb + 1];
    for (int base = start + wv * 64; base < end; base += 256) {
        int n = end - base; if (n > 64) n = 64;
        int key = 0, wb = 0;
        if (lane < n) {
            int2 r = rec[base + lane];
            key = r.x; wb = r.y;
        }
        int j = 0;
        for (; j + 8 <= n; j += 8) {
            unsigned int v[8]; float w[8]; int dl[8];
#pragma unroll
            for (int u = 0; u < 8; u++) {
                int k2 = __builtin_amdgcn_readlane(key, j + u);
                w[u] = __int_as_float(__builtin_amdgcn_readlane(wb, j + u));
                dl[u] = (unsigned)k2 >> 17;
                int s = k2 & 131071;
                const unsigned int* rowp = (const unsigned int*)(support + (long)s * 128);
                v[u] = rowp[lane];
            }
#pragma unroll
            for (int u = 0; u < 8; u++) {
                float lo = w[u] * b2f((ushort_t)(v[u] & 0xffffu));
                float hi = w[u] * b2f((ushort_t)(v[u] >> 16));
                atomicAdd(&acc[dl[u] * 128 + lane * 2], lo);
                atomicAdd(&acc[dl[u] * 128 + lane * 2 + 1], hi);
            }
        }
        for (; j < n; j++) {
            int k2 = __builtin_amdgcn_readlane(key, j);
            float wj = __int_as_float(__builtin_amdgcn_readlane(wb, j));
            int dl = (unsigned)k2 >> 17;
            int s = k2 & 131071;
            const unsigned int* rowp = (const unsigned int*)(support + (long)s * 128);
            unsigned int v = rowp[lane];
            atomicAdd(&acc[dl * 128 + lane * 2], wj * b2f((ushort_t)(v & 0xffffu)));
            atomicAdd(&acc[dl * 128 + lane * 2 + 1], wj * b2f((ushort_t)(v >> 16)));
        }
    }
    __syncthreads();

    // LayerNorm: each wave handles 16 of the 64 nodes
    float g0 = gamma[lane * 2], g1 = gamma[lane * 2 + 1];
    float b0 = beta[lane * 2], b1 = beta[lane * 2 + 1];
#pragma unroll 1
    for (int i = 0; i < 16; i++) {
        int ln = wv * 16 + i;
        int node = sb * 64 + ln;
        if (node >= n_nodes) break;
        float ax = acc[ln * 128 + lane * 2];
        float ay = acc[ln * 128 + lane * 2 + 1];
        float2 r = *(const float2*)(out + (long)node * 128 + lane * 2);
        float tx = ax + r.x, ty = ay + r.y;
        float s = tx + ty;
        float ss = tx * tx + ty * ty;
#pragma unroll
        for (int off = 1; off < 64; off <<= 1) {
            s += __shfl_xor(s, off, 64);
            ss += __shfl_xor(ss, off, 64);
        }
        float mean = s * (1.0f / 128.0f);
        float var = ss * (1.0f / 128.0f) - mean * mean;
        float rstd = rsqrtf(var + LN_EPS);
        float2 o;
        o.x = (tx - mean) * rstd * g0 + b0;
        o.y = (ty - mean) * rstd * g1 + b1;
        *(float2*)(out + (long)node * 128 + lane * 2) = o;
    }
}

extern "C" void kernel_launch(void* const* d_in, const int* in_sizes, int n_in,
                              void* d_out, int out_size, void* d_ws, size_t ws_size,
                              hipStream_t stream) {
    const float* x      = (const float*)d_in[0];
    const float* weight = (const float*)d_in[1];
    const float* bias   = (const float*)d_in[2];
    const float* res_w  = (const float*)d_in[3];
    const float* res_b  = (const float*)d_in[4];
    const float* gamma  = (const float*)d_in[5];
    const float* beta   = (const float*)d_in[6];
    const float* ew     = (const float*)d_in[7];
    const int*   ei     = (const int*)d_in[8];

    const int E = in_sizes[7];
    const int n_nodes = in_sizes[0] / D_IN;
    const int chunk = (E + NCHUNK - 1) / NCHUNK;
    float* out = (float*)d_out;

    // workspace layout (256B-aligned), total ~54 MB
    char* ws = (char*)d_ws;
    size_t off = 0;
    auto alloc = [&](size_t bytes) { void* p = ws + off; off = (off + bytes + 255) & ~(size_t)255; return p; };
    ushort_t* wt      = (ushort_t*)alloc(256 * 256 * 2);                 // 128 KB
    ushort_t* support = (ushort_t*)alloc((size_t)n_nodes * 128 * 2);     // 25.6 MB
    int* cntmat       = (int*)alloc((size_t)NCHUNK * NSUB * 4);          // 2 MB  [chunk][sub]
    int* rowsum       = (int*)alloc(NSUB * 4);                           // 8 KB
    int* sub_base     = (int*)alloc((NSUB + 1) * 4);                     // 8 KB
    int2* rec         = (int2*)alloc((size_t)E * 8);                     // 25.6 MB

    const int gb = (n_nodes + 63) / 64;
    const int nsub_use = (n_nodes + 63) >> 6;

    k_transpose<<<256, 256, 0, stream>>>(weight, res_w, wt);
    k_gemm_count<<<gb + NCHUNK, 256, 0, stream>>>(x, wt, bias, res_b, support, out,
                                                  ei, cntmat, n_nodes, E, chunk, gb);
    k_scan1<<<NSUB, 256, 0, stream>>>(cntmat, rowsum);
    k_scan2<<<1, 256, 0, stream>>>(rowsum, sub_base, E);
    k_part<<<NCHUNK, 256, 0, stream>>>(ei, ew, cntmat, sub_base, rec, E, chunk);
    k_agg_ln<<<nsub_use, 256, 0, stream>>>(support, sub_base, rec, gamma, beta, out, n_nodes);
}